// Round 2
// baseline (457.007 us; speedup 1.0000x reference)
//
#include <hip/hip_runtime.h>

// Problem (all fp32 in/out): x1[o,n,c] = sum_p X[n,p] * (dags*W)[o,p,c]
//          plus dags passthrough and reg[o] = 0.001*sum(W^2).
// N=200000, D=64 (P=C=64), O=8.
// d_out (fp32): x1 (102,400,000) | dags (32,768) | reg (8).
// Core: bf16 MFMA (fp32 VALU would be compute-bound at ~83us > 73us mem floor);
// bf16 rounding error ~0.5% << 2% threshold.

typedef short short8 __attribute__((ext_vector_type(8)));   // 8 bf16 = 4 VGPRs (MFMA A/B frag)
typedef float f32x4 __attribute__((ext_vector_type(4)));    // MFMA C/D frag / float4

#define NROWS    200000
#define DAGS_OFF 102400000
#define REG_OFF  102432768
#define O_STRIDE 12800000    // 200000*64

__device__ __forceinline__ unsigned short f2bf(float f) {
    union { float f; unsigned int i; } v; v.f = f;
    unsigned int x = v.i;
    unsigned int r = (x + 0x7fffu + ((x >> 16) & 1u)) >> 16;   // RNE
    return (unsigned short)r;
}

// ---------------------------------------------------------------------------
// Prep: WMt[o][c][p] = bf16(dags[o][p][c] * W[o][p][c]) into ws (64 KB),
//       dags fp32 passthrough, reg[o] = 0.001 * sum(W[o]^2) fp32.
// One block per o, 256 threads.
// ---------------------------------------------------------------------------
__global__ __launch_bounds__(256) void prep_kernel(
    const float* __restrict__ dags,
    const float* __restrict__ W,
    unsigned short* __restrict__ wmt,
    float* __restrict__ out)
{
    const int o = blockIdx.x;
    const int t = threadIdx.x;
    const float* dg = dags + o * 4096;
    const float* w  = W    + o * 4096;
    unsigned short* wt   = wmt + o * 4096;
    float* outd = out + DAGS_OFF + o * 4096;

    float s = 0.f;
    #pragma unroll
    for (int i = 0; i < 16; ++i) {
        int e = i * 256 + t;          // e = p*64 + c  (coalesced fp32 reads)
        int p = e >> 6, c = e & 63;
        float dv = dg[e];
        float wv = w[e];
        wt[c * 64 + p] = f2bf(dv * wv);   // transposed bf16 write (tiny, L2-absorbed)
        outd[e] = dv;                      // dags passthrough
        s += wv * wv;
    }
    // block reduction for reg
    #pragma unroll
    for (int off = 32; off > 0; off >>= 1) s += __shfl_down(s, off);
    __shared__ float red[4];
    if ((t & 63) == 0) red[t >> 6] = s;
    __syncthreads();
    if (t == 0) {
        out[REG_OFF + o] = 0.001f * (red[0] + red[1] + red[2] + red[3]);
    }
}

// ---------------------------------------------------------------------------
// Main: per block 64 rows of X, all 8 o's. MFMA 16x16x32 bf16, transposed
// trick: A = WMt tile (c-major), B = X rows. D lane holds fixed row n=lane&15,
// 4 consecutive c per reg-quad -> float4 stores.
// ---------------------------------------------------------------------------
__global__ __launch_bounds__(256) void gemm_kernel(
    const float* __restrict__ X,
    const unsigned short* __restrict__ wmt,
    float* __restrict__ out)
{
    // [oo][c][chunk] with chunk XOR-swizzle; 32 KB
    __shared__ short8 WMts[4][64][8];

    const int t    = threadIdx.x;
    const int w    = t >> 6;        // wave 0..3
    const int lane = t & 63;
    const int r    = lane & 15;     // B col (X row within tile) / A row (c)
    const int q    = lane >> 4;     // quad 0..3

    const int nb = blockIdx.x * 64 + w * 16 + r;   // this lane's X row

    // X fragment (MFMA B operand): lane holds X[nb][k], k = q*8..q*8+7 (+32).
    // fp32 loads (4x16B, coalesced within quad), convert to bf16 in-register;
    // held across all 8 o's so X is fetched from HBM exactly once.
    const f32x4 xf0 = *reinterpret_cast<const f32x4*>(X + nb * 64 + q * 8);
    const f32x4 xf1 = *reinterpret_cast<const f32x4*>(X + nb * 64 + q * 8 + 4);
    const f32x4 xf2 = *reinterpret_cast<const f32x4*>(X + nb * 64 + 32 + q * 8);
    const f32x4 xf3 = *reinterpret_cast<const f32x4*>(X + nb * 64 + 32 + q * 8 + 4);
    short8 xk0, xk1;
    #pragma unroll
    for (int j = 0; j < 4; ++j) {
        xk0[j]     = (short)f2bf(xf0[j]);
        xk0[4 + j] = (short)f2bf(xf1[j]);
        xk1[j]     = (short)f2bf(xf2[j]);
        xk1[4 + j] = (short)f2bf(xf3[j]);
    }

    #pragma unroll
    for (int phase = 0; phase < 2; ++phase) {
        // stage 4 o's of WMt (32 KB) into LDS, 16B chunks, XOR swizzle on chunk idx
        {
            const unsigned short* src = wmt + phase * 4 * 4096;
            #pragma unroll
            for (int i = 0; i < 8; ++i) {
                int g   = i * 256 + t;       // 2048 chunks total
                int oo  = g >> 9;            // 512 chunks per o
                int rem = g & 511;
                int c   = rem >> 3;
                int j   = rem & 7;
                short8 v = *reinterpret_cast<const short8*>(src + oo * 4096 + c * 64 + j * 8);
                WMts[oo][c][j ^ (c & 7)] = v;
            }
        }
        __syncthreads();

        #pragma unroll
        for (int oo = 0; oo < 4; ++oo) {
            const int o = phase * 4 + oo;
            float* outp = out + o * O_STRIDE + nb * 64;
            #pragma unroll
            for (int ct = 0; ct < 4; ++ct) {
                const int c = ct * 16 + r;     // A-operand row (c index); c&7 == r&7
                short8 a0 = WMts[oo][c][q       ^ (r & 7)];
                short8 a1 = WMts[oo][c][(4 + q) ^ (r & 7)];
                f32x4 acc = {0.f, 0.f, 0.f, 0.f};
                acc = __builtin_amdgcn_mfma_f32_16x16x32_bf16(a0, xk0, acc, 0, 0, 0);
                acc = __builtin_amdgcn_mfma_f32_16x16x32_bf16(a1, xk1, acc, 0, 0, 0);
                // lane holds x1[nb][ct*16 + 4q + {0..3}] -> float4 store
                *reinterpret_cast<f32x4*>(outp + ct * 16 + q * 4) = acc;
            }
        }
        __syncthreads();   // before restaging LDS in next phase
    }
}

extern "C" void kernel_launch(void* const* d_in, const int* in_sizes, int n_in,
                              void* d_out, int out_size, void* d_ws, size_t ws_size,
                              hipStream_t stream)
{
    const float* X    = (const float*)d_in[0];
    const float* dags = (const float*)d_in[1];
    const float* W    = (const float*)d_in[2];
    float* out = (float*)d_out;
    unsigned short* wmt = (unsigned short*)d_ws;   // 64 KB scratch

    prep_kernel<<<8, 256, 0, stream>>>(dags, W, wmt, out);
    gemm_kernel<<<NROWS / 64, 256, 0, stream>>>(X, wmt, out);
}